// Round 8
// baseline (210.671 us; speedup 1.0000x reference)
//
#include <hip/hip_runtime.h>
#include <cstdint>
#include <cstddef>

#define DIMC 384
#define DST  16
#define LLEN 4096
#define NB   4
#define PDIM 800   // 2*DIMC + 2*DST
#define NCH  128
#define CL   32
#define KDIM 384
#define NPAD 896   // W_proj rows padded to 7*128

typedef __attribute__((ext_vector_type(8))) short bf16x8;
typedef __attribute__((ext_vector_type(4))) float f32x4;

#define GLOAD16(g, l) __builtin_amdgcn_global_load_lds( \
    (const __attribute__((address_space(1))) uint32_t*)(g), \
    (__attribute__((address_space(3))) uint32_t*)(l), 16, 0, 0)

__device__ __forceinline__ float softplus_f(float v) {
    if (v > 20.f) return v;
    return logf(1.f + __expf(v));
}

__device__ __forceinline__ ushort f2bf(float x) {
    uint32_t u = __float_as_uint(x);
    uint32_t r = (u + 0x7FFFu + ((u >> 16) & 1u)) >> 16;
    return (ushort)r;
}
__device__ __forceinline__ float bf2f(ushort u) {
    return __uint_as_float(((uint32_t)u) << 16);
}

// Both weight casts in one launch. W_proj padded to NPAD rows with zeros.
__global__ __launch_bounds__(256)
void cast_weights(const float* __restrict__ Wp, const float* __restrict__ Wo,
                  ushort* __restrict__ outp, ushort* __restrict__ outo)
{
    const int np = NPAD * KDIM;
    const int no = DIMC * KDIM;
    int i = (blockIdx.x * 256 + threadIdx.x) * 4;
    if (i < np) {
        ushort4 s;
        if (i < PDIM * KDIM) {
            float4 v = *(const float4*)(Wp + i);
            s.x = f2bf(v.x); s.y = f2bf(v.y); s.z = f2bf(v.z); s.w = f2bf(v.w);
        } else { s.x = 0; s.y = 0; s.z = 0; s.w = 0; }
        *(ushort4*)(outp + i) = s;
    } else {
        int k = i - np;
        if (k < no) {
            float4 v = *(const float4*)(Wo + k);
            ushort4 s; s.x = f2bf(v.x); s.y = f2bf(v.y); s.z = f2bf(v.z); s.w = f2bf(v.w);
            *(ushort4*)(outo + k) = s;
        }
    }
}

// in: [B][R=384][C=4096] fp32 ; out: [B][C][R] bf16. 64x64 LDS tile.
__global__ __launch_bounds__(256)
void transpose_cast(const float* __restrict__ in, ushort* __restrict__ out)
{
    __shared__ float t[64][65];
    const int tid = threadIdx.x;
    const int b  = blockIdx.z;
    const int c0 = blockIdx.y * 64;
    const int l0 = blockIdx.x * 64;
    const float* ip = in + ((size_t)b * DIMC + c0) * LLEN + l0;
    #pragma unroll
    for (int r = 0; r < 4; ++r) {
        int cl = (tid >> 4) + r * 16;
        int l4 = (tid & 15) * 4;
        float4 v = *(const float4*)(ip + (size_t)cl * LLEN + l4);
        t[cl][l4 + 0] = v.x; t[cl][l4 + 1] = v.y;
        t[cl][l4 + 2] = v.z; t[cl][l4 + 3] = v.w;
    }
    __syncthreads();
    ushort* op = out + ((size_t)b * LLEN + l0) * DIMC + c0;
    #pragma unroll
    for (int r = 0; r < 4; ++r) {
        int ll = (tid >> 4) + r * 16;
        int c4 = (tid & 15) * 4;
        ushort4 s;
        s.x = f2bf(t[c4 + 0][ll]); s.y = f2bf(t[c4 + 1][ll]);
        s.z = f2bf(t[c4 + 2][ll]); s.w = f2bf(t[c4 + 3][ll]);
        *(ushort4*)(op + (size_t)ll * DIMC + c4) = s;
    }
}

// bf16 MFMA GEMM. Tile 128(m) x 128(n), BK=32, 4 waves in 2x2, each wave 64x64 out.
// EPI 0: proj epilogue — x_in/delta stored TIME-MAJOR [b][l][d] bf16.
// EPI 1: out epilogue (store [b][n][l] fp32 + bias).
template<int EPI>
__global__ __launch_bounds__(256)
void mfma_gemm(const ushort* __restrict__ Abf, const ushort* __restrict__ Wbf,
               const float* __restrict__ bias, const float* __restrict__ dt_bias,
               ushort* __restrict__ o_x, ushort* __restrict__ o_dt,
               float* __restrict__ o_Bm, float* __restrict__ o_Cm,
               float* __restrict__ o_out)
{
    __shared__ ushort Alds[128 * 32];   // 8 KB
    __shared__ ushort Blds[128 * 32];   // 8 KB

    const int tid = threadIdx.x;
    const int m0  = blockIdx.x * 128;
    const int n0  = blockIdx.y * 128;
    const int w   = tid >> 6;
    const int ln  = tid & 63;
    const int wr  = (w >> 1) * 64;    // wave row base
    const int wc  = (w & 1) * 64;     // wave col base
    const int fr  = ln & 15;
    const int fg  = ln >> 4;

    const int srow = tid >> 2;        // 0..63
    const int sg   = tid & 3;

    const ushort* Ag = Abf + (size_t)m0 * KDIM;
    const ushort* Bg = Wbf + (size_t)n0 * KDIM;

    f32x4 acc[4][4];
    #pragma unroll
    for (int i = 0; i < 4; ++i)
        #pragma unroll
        for (int j = 0; j < 4; ++j)
            acc[i][j] = (f32x4){0.f, 0.f, 0.f, 0.f};

    const int r1 = srow + 64;
    const int a0 = sg ^ ((srow >> 1) & 3);
    const int a1 = sg ^ ((r1 >> 1) & 3);

    for (int k0 = 0; k0 < KDIM; k0 += 32) {
        if (k0) __syncthreads();
        GLOAD16(Ag + (size_t)srow * KDIM + k0 + a0 * 8, &Alds[tid * 8]);
        GLOAD16(Ag + (size_t)r1   * KDIM + k0 + a1 * 8, &Alds[2048 + tid * 8]);
        GLOAD16(Bg + (size_t)srow * KDIM + k0 + a0 * 8, &Blds[tid * 8]);
        GLOAD16(Bg + (size_t)r1   * KDIM + k0 + a1 * 8, &Blds[2048 + tid * 8]);
        __syncthreads();
        bf16x8 af[4], bfv[4];
        #pragma unroll
        for (int i = 0; i < 4; ++i) {
            int r = wr + i * 16 + fr;
            af[i] = *(const bf16x8*)&Alds[r * 32 + ((fg ^ ((r >> 1) & 3)) << 3)];
        }
        #pragma unroll
        for (int j = 0; j < 4; ++j) {
            int r = wc + j * 16 + fr;
            bfv[j] = *(const bf16x8*)&Blds[r * 32 + ((fg ^ ((r >> 1) & 3)) << 3)];
        }
        #pragma unroll
        for (int i = 0; i < 4; ++i)
            #pragma unroll
            for (int j = 0; j < 4; ++j)
                acc[i][j] = __builtin_amdgcn_mfma_f32_16x16x32_bf16(af[i], bfv[j], acc[i][j], 0, 0, 0);
    }

    const int b   = m0 / LLEN;
    const int ml0 = m0 - b * LLEN;
    #pragma unroll
    for (int j = 0; j < 4; ++j) {
        const int n = n0 + wc + j * 16 + fr;
        #pragma unroll
        for (int i = 0; i < 4; ++i) {
            const int l = ml0 + wr + i * 16 + fg * 4;
            f32x4 v = acc[i][j];
            if (EPI == 0) {
                if (n < DIMC) {
                    const float bb = bias[n];
                    #pragma unroll
                    for (int r = 0; r < 4; ++r)
                        o_x[((size_t)b * LLEN + l + r) * DIMC + n] = f2bf(v[r] + bb);
                } else if (n < 2 * DIMC) {
                    const int d = n - DIMC;
                    const float bb = bias[n] + dt_bias[d];
                    #pragma unroll
                    for (int r = 0; r < 4; ++r)
                        o_dt[((size_t)b * LLEN + l + r) * DIMC + d] = f2bf(softplus_f(v[r] + bb));
                } else if (n < 2 * DIMC + DST) {
                    const int s = n - 2 * DIMC;
                    const float bb = bias[n];
                    #pragma unroll
                    for (int r = 0; r < 4; ++r)
                        o_Bm[((size_t)b * LLEN + l + r) * DST + s] = v[r] + bb;
                } else if (n < PDIM) {
                    const int s = n - 2 * DIMC - DST;
                    const float bb = bias[n];
                    #pragma unroll
                    for (int r = 0; r < 4; ++r)
                        o_Cm[((size_t)b * LLEN + l + r) * DST + s] = v[r] + bb;
                }
            } else {
                const float bb = bias[n];
                float4 st; st.x = v[0] + bb; st.y = v[1] + bb; st.z = v[2] + bb; st.w = v[3] + bb;
                *(float4*)(o_out + ((size_t)b * DIMC + n) * LLEN + l) = st;
            }
        }
    }
}

// ---- Chunked scan, time-major bf16 dt/x ([b][l][d]) ----
__global__ __launch_bounds__(384)
void scan_part1(const ushort* __restrict__ dt_t, const ushort* __restrict__ x_t,
                const float* __restrict__ Bm, const float* __restrict__ A_log,
                float* __restrict__ Pc, float* __restrict__ Qc)
{
    __shared__ float Bs[CL][DST];
    const int d   = threadIdx.x;
    const int b   = blockIdx.x >> 7;          // NCH = 128
    const int chk = blockIdx.x & (NCH - 1);
    const int l0  = chk * CL;

    if (d < (CL * DST) / 4)
        ((float4*)&Bs[0][0])[d] =
            ((const float4*)(Bm + ((size_t)b * LLEN + l0) * DST))[d];

    float Av[DST];
    #pragma unroll
    for (int r = 0; r < 4; ++r) {
        float4 v = *(const float4*)(A_log + d * DST + r * 4);
        Av[r*4+0] = -__expf(v.x); Av[r*4+1] = -__expf(v.y);
        Av[r*4+2] = -__expf(v.z); Av[r*4+3] = -__expf(v.w);
    }
    __syncthreads();

    const ushort* dtp = dt_t + ((size_t)b * LLEN + l0) * DIMC + d;
    const ushort* xp  = x_t  + ((size_t)b * LLEN + l0) * DIMC + d;

    float P[DST], q[DST];
    #pragma unroll
    for (int n = 0; n < DST; ++n) { P[n] = 1.f; q[n] = 0.f; }

    for (int t0 = 0; t0 < CL; t0 += 4) {
        float dts[4], xs[4];
        #pragma unroll
        for (int j = 0; j < 4; ++j) {
            dts[j] = bf2f(dtp[(size_t)(t0 + j) * DIMC]);
            xs[j]  = bf2f(xp[(size_t)(t0 + j) * DIMC]);
        }
        #pragma unroll
        for (int j = 0; j < 4; ++j) {
            const float dt  = dts[j];
            const float dtx = dt * xs[j];
            #pragma unroll
            for (int n = 0; n < DST; ++n) {
                float a = __expf(dt * Av[n]);
                P[n] *= a;
                q[n] = fmaf(a, q[n], dtx * Bs[t0 + j][n]);
            }
        }
    }
    const size_t o = (((size_t)b * NCH + chk) * DIMC + d) * DST;
    #pragma unroll
    for (int r = 0; r < 4; ++r) {
        *(float4*)(Pc + o + r * 4) = *(float4*)&P[r * 4];
        *(float4*)(Qc + o + r * 4) = *(float4*)&q[r * 4];
    }
}

__global__ __launch_bounds__(256)
void scan_carry(const float* __restrict__ Pc, const float* __restrict__ Qc,
                float* __restrict__ Hin)
{
    const int idx = blockIdx.x * 256 + threadIdx.x;   // over B*DIMC*16
    const int bd  = idx >> 4;
    const int n   = idx & 15;
    const int b   = bd / DIMC;
    const int d   = bd - b * DIMC;
    float h = 0.f;
    for (int chk = 0; chk < NCH; ++chk) {
        const size_t o = (((size_t)b * NCH + chk) * DIMC + d) * DST + n;
        Hin[o] = h;
        h = fmaf(Pc[o], h, Qc[o]);
    }
}

// Pass 3: local rescan from Hin; y written directly as bf16 transposed [b][l][d].
__global__ __launch_bounds__(384)
void scan_part3(const ushort* __restrict__ dt_t, const ushort* __restrict__ x_t,
                const float* __restrict__ Bm, const float* __restrict__ Cm,
                const float* __restrict__ A_log, const float* __restrict__ Dv,
                const float* __restrict__ Hin, ushort* __restrict__ y_bfT)
{
    __shared__ float Bs[CL][DST];
    __shared__ float Cs[CL][DST];
    const int d   = threadIdx.x;
    const int b   = blockIdx.x >> 7;
    const int chk = blockIdx.x & (NCH - 1);
    const int l0  = chk * CL;

    if (d < 128)
        ((float4*)&Bs[0][0])[d] =
            ((const float4*)(Bm + ((size_t)b * LLEN + l0) * DST))[d];
    else if (d < 256)
        ((float4*)&Cs[0][0])[d - 128] =
            ((const float4*)(Cm + ((size_t)b * LLEN + l0) * DST))[d - 128];

    float Av[DST];
    #pragma unroll
    for (int r = 0; r < 4; ++r) {
        float4 v = *(const float4*)(A_log + d * DST + r * 4);
        Av[r*4+0] = -__expf(v.x); Av[r*4+1] = -__expf(v.y);
        Av[r*4+2] = -__expf(v.z); Av[r*4+3] = -__expf(v.w);
    }
    const float Dd = Dv[d];
    __syncthreads();

    float h[DST];
    const size_t ho = (((size_t)b * NCH + chk) * DIMC + d) * DST;
    #pragma unroll
    for (int r = 0; r < 4; ++r)
        *(float4*)&h[r * 4] = *(const float4*)(Hin + ho + r * 4);

    const ushort* dtp = dt_t + ((size_t)b * LLEN + l0) * DIMC + d;
    const ushort* xp  = x_t  + ((size_t)b * LLEN + l0) * DIMC + d;
    ushort* yp = y_bfT + ((size_t)b * LLEN + l0) * DIMC + d;

    for (int t0 = 0; t0 < CL; t0 += 4) {
        float dts[4], xs[4];
        #pragma unroll
        for (int j = 0; j < 4; ++j) {
            dts[j] = bf2f(dtp[(size_t)(t0 + j) * DIMC]);
            xs[j]  = bf2f(xp[(size_t)(t0 + j) * DIMC]);
        }
        #pragma unroll
        for (int j = 0; j < 4; ++j) {
            const float dt  = dts[j];
            const float xx  = xs[j];
            const float dtx = dt * xx;
            float yv = Dd * xx;
            #pragma unroll
            for (int n = 0; n < DST; ++n) {
                float a = __expf(dt * Av[n]);
                h[n] = fmaf(a, h[n], dtx * Bs[t0 + j][n]);
                yv = fmaf(h[n], Cs[t0 + j][n], yv);
            }
            yp[(size_t)(t0 + j) * DIMC] = f2bf(yv);
        }
    }
}

extern "C" void kernel_launch(void* const* d_in, const int* in_sizes, int n_in,
                              void* d_out, int out_size, void* d_ws, size_t ws_size,
                              hipStream_t stream)
{
    const float* x      = (const float*)d_in[0];
    const float* W_proj = (const float*)d_in[1];
    const float* b_proj = (const float*)d_in[2];
    const float* A_log  = (const float*)d_in[3];
    const float* Dv     = (const float*)d_in[4];
    const float* dt_b   = (const float*)d_in[5];
    const float* W_out  = (const float*)d_in[6];
    const float* b_out  = (const float*)d_in[7];
    float* out = (float*)d_out;

    const size_t szBD = (size_t)NB * DIMC * LLEN;          // 6,291,456
    const size_t szBC = (size_t)NB * LLEN * DST;           //   262,144
    const size_t szPQ = (size_t)NB * NCH * DIMC * DST;     // 3,145,728
    ushort* x_bf16  = (ushort*)d_ws;                       // [B][L][D] bf16 (scan x)
    ushort* dt_bf16 = x_bf16 + szBD;                       // [B][L][D] bf16
    float*  Bmw  = (float*)(dt_bf16 + szBD);
    float*  Cmw  = Bmw + szBC;
    float*  Pc   = Cmw + szBC;
    float*  Qc   = Pc + szPQ;
    float*  Hin  = Qc + szPQ;
    ushort* x_bfT = (ushort*)(Hin + szPQ);                 // [B][L][K] bf16 (GEMM1 A)
    ushort* y_bfT = x_bfT + szBD;                          // [B][L][K] bf16 (GEMM2 A)
    ushort* Wp_bf = y_bfT + szBD;                          // [896][384] bf16
    ushort* Wo_bf = Wp_bf + (size_t)NPAD * KDIM;           // [384][384] bf16

    cast_weights<<<(NPAD * KDIM + DIMC * KDIM) / 1024, 256, 0, stream>>>(
        W_proj, W_out, Wp_bf, Wo_bf);
    dim3 tg(LLEN / 64, DIMC / 64, NB);
    transpose_cast<<<tg, 256, 0, stream>>>(x, x_bfT);

    dim3 g1((NB * LLEN) / 128, NPAD / 128);
    mfma_gemm<0><<<g1, 256, 0, stream>>>(x_bfT, Wp_bf, b_proj, dt_b,
                                         x_bf16, dt_bf16, Bmw, Cmw, nullptr);

    scan_part1<<<NB * NCH, 384, 0, stream>>>(dt_bf16, x_bf16, Bmw, A_log, Pc, Qc);
    scan_carry<<<(NB * DIMC * DST) / 256, 256, 0, stream>>>(Pc, Qc, Hin);
    scan_part3<<<NB * NCH, 384, 0, stream>>>(dt_bf16, x_bf16, Bmw, Cmw,
                                             A_log, Dv, Hin, y_bfT);

    dim3 g2((NB * LLEN) / 128, DIMC / 128);
    mfma_gemm<1><<<g2, 256, 0, stream>>>(y_bfT, Wo_bf, b_out, nullptr,
                                         nullptr, nullptr, nullptr, nullptr,
                                         out);
}